// Round 12
// baseline (94.845 us; speedup 1.0000x reference)
//
#include <hip/hip_runtime.h>
#include <hip/hip_bf16.h>
#include <math.h>

// S4D joint kernel via MFMA factorization, ILP-restructured transcendentals.
//   out[k][h,l] = 2*Re( sum_n c_k[h,n] * exp(dtA[h,n]*l) ),  k=0..3
// Factor l = 64*l1 + l2: exp(dtA*l) = P_n(l1)*Q_n(l2).
//  -> real GEMM (64 x 64 x 64) per (h,k), mfma_f32_16x16x32_f16, f16 hi/lo
//     split (drop lo*lo), residual ~3e-5.
// One block per h (256 thr); wave w computes output k=w.
//  stage1 (tid<32): params; f64 only for exp(log_dt) + angle products.
//  stage2: thread -> (l2=tid>>2, 8 modes): 8 INDEPENDENT anchors, half8
//          assembly, 4x ds_write_b128 (no rotation chains, no scalar writes).
//  stage3: per mode TWO independent anchors (tm=0, tm=2) + one G-mult each
//          (chain depth 1, 16 independent streams per wave).
//  stage4: 16 tiles x 6 MFMA + nontemporal coalesced dword stores.
// Assumes N2=32, L=4096.

typedef float    f32x2 __attribute__((ext_vector_type(2)));
typedef float    f32x4 __attribute__((ext_vector_type(4)));
typedef _Float16 half8 __attribute__((ext_vector_type(8)));

#define NMODES 32

__global__ __launch_bounds__(256, 4) void s4d_mfma_kernel(
    const float* __restrict__ C_r,
    const float* __restrict__ Ca_r,
    const float* __restrict__ E_r,
    const float* __restrict__ log_dt,
    const float* __restrict__ log_A_real,
    const float* __restrict__ A_imag,
    float* __restrict__ out,
    int H, int N2, int L)
{
    const int h    = blockIdx.x;
    const int tid  = threadIdx.x;
    const int w    = tid >> 6;   // wave id = output k
    const int lane = tid & 63;
    const int l15  = lane & 15;
    const int lgrp = lane >> 4;

    __shared__ _Float16 Bt_hi[64][72];   // [l2][kk] kk<32: Qr, kk>=32: -Qi
    __shared__ _Float16 Bt_lo[64][72];
    __shared__ f32x4 s_anc[NMODES];      // {dre, dim_hi(rev), dim_lo(rev), 0}
    __shared__ f32x2 s_G  [NMODES];      // G = exp(dtA*1024)
    __shared__ f32x2 s_coef[4][NMODES];  // 2*coef_k

    // ---- stage 1: per-mode params (threads 0..31) ----
    if (tid < N2) {
        const int n = tid;
        const double ldt  = (double)log_dt[h];
        const double dtd  = exp(ldt);                       // the one f64 exp
        const float  dtf  = (float)dtd;
        const float  aref = -__expf(log_A_real[h * N2 + n]);
        const float  aimf = A_imag[h * N2 + n];
        const float  dre  = aref * dtf;
        const double dim  = (double)aimf * dtd;
        const double dimrev = dim * 0.15915494309189535;    // /(2pi)

        // hi: 12-bit mantissa so hi*x exact for integer x <= 4032
        float hi = (float)dimrev;
        hi = __uint_as_float(__float_as_uint(hi) & 0xFFFFF000u);
        const float lo = (float)(dimrev - (double)hi);

        // r = exp(dtA) pieces for the scale factor
        const float trev = (float)(dimrev - rint(dimrev));
        const float sn = __builtin_amdgcn_sinf(trev);
        const float er = __expf(dre);

        // G = exp(dtA*1024)
        const double d1024 = dimrev * 1024.0;
        const float  g_t   = (float)(d1024 - rint(d1024));
        const float  g_er  = __expf(dre * 1024.0f);
        f32x2 G;
        G.x = g_er * __builtin_amdgcn_cosf(g_t);
        G.y = g_er * __builtin_amdgcn_sinf(g_t);

        // scale = (exp(dtA)-1)/A, stable numerator:
        // nr = expm1(dre) + er*(cos-1), cos-1 = -2*sin^2(trev/2)
        const float sh  = __builtin_amdgcn_sinf(0.5f * trev);
        const float cs1 = -2.f * sh * sh;
        const float nr  = expm1f(dre) + er * cs1;
        const float ni  = er * sn;
        const float den = aref * aref + aimf * aimf;
        const float scr = (nr * aref + ni * aimf) / den;
        const float sci = (ni * aref - nr * aimf) / den;

        const float cr  = C_r [(h * N2 + n) * 2 + 0];
        const float ci  = C_r [(h * N2 + n) * 2 + 1];
        const float ar  = Ca_r[(h * N2 + n) * 2 + 0];
        const float ai  = Ca_r[(h * N2 + n) * 2 + 1];
        const float exr = E_r [(h * N2 + n) * 2 + 0];
        const float exi = E_r [(h * N2 + n) * 2 + 1];
        const float cmr = cr * scr - ci * sci;   // C_main
        const float cmi = cr * sci + ci * scr;
        const float car = ar * scr - ai * sci;   // C_aux_d
        const float cai = ar * sci + ai * scr;
        const float emr = exr * cmr - exi * cmi; // E_main
        const float emi = exr * cmi + exi * cmr;
        const float ear = exr * car - exi * cai; // E_aux
        const float eai = exr * cai + exi * car;

        f32x2 c;
        c.x = 2.f*cmr; c.y = 2.f*cmi; s_coef[0][n] = c;
        c.x = 2.f*emr; c.y = 2.f*emi; s_coef[1][n] = c;
        c.x = 2.f*car; c.y = 2.f*cai; s_coef[2][n] = c;
        c.x = 2.f*ear; c.y = 2.f*eai; s_coef[3][n] = c;

        f32x4 a;
        a.x = dre; a.y = hi; a.z = lo; a.w = 0.f;
        s_anc[n] = a;
        s_G[n] = G;
    }
    __syncthreads();

    // ---- stage 2: Q table -> Bt; 8 independent anchors, b128 writes ----
    {
        const int l2 = tid >> 2;          // 0..63
        const int nb = (tid & 3) * 8;     // mode group base
        const float l2f = (float)l2;
        half8 qh, ql, mh, ml;
#pragma unroll
        for (int j = 0; j < 8; ++j) {
            const f32x4 an = s_anc[nb + j];
            float t = an.y * l2f;  t -= rintf(t);
            t = fmaf(an.z, l2f, t); t -= rintf(t);
            const float er = __expf(an.x * l2f);
            const float qr = er * __builtin_amdgcn_cosf(t);
            const float qi = er * __builtin_amdgcn_sinf(t);
            const _Float16 qrh = (_Float16)qr;
            qh[j] = qrh;
            ql[j] = (_Float16)(qr - (float)qrh);
            const float mi = -qi;
            const _Float16 mih = (_Float16)mi;
            mh[j] = mih;
            ml[j] = (_Float16)(mi - (float)mih);
        }
        *(half8*)&Bt_hi[l2][nb]      = qh;
        *(half8*)&Bt_hi[l2][nb + 32] = mh;
        *(half8*)&Bt_lo[l2][nb]      = ql;
        *(half8*)&Bt_lo[l2][nb + 32] = ml;
    }

    // ---- stage 3: A fragments in regs; 2 anchors + 2 G-mults per mode ----
    // a-frag(tm,kt): lane holds A[16*tm + l15][32*kt + 8*lgrp + j]
    half8 ahi[4][2], alo[4][2];
    {
        const int nbw = lgrp * 8;
        const float row0 = 64.f * (float)l15;      // tm=0 anchor row (exact)
        const float row2 = 2048.f + row0;          // tm=2 anchor row (exact)
#pragma unroll
        for (int j = 0; j < 8; ++j) {
            const int n = nbw + j;
            const f32x4 an = s_anc[n];
            const f32x2 c  = s_coef[w][n];
            const f32x2 G  = s_G[n];

            float t0 = an.y * row0;  t0 -= rintf(t0);
            t0 = fmaf(an.z, row0, t0); t0 -= rintf(t0);
            const float e0 = __expf(an.x * row0);
            const float p0r = e0 * __builtin_amdgcn_cosf(t0);
            const float p0i = e0 * __builtin_amdgcn_sinf(t0);

            float t2 = an.y * row2;  t2 -= rintf(t2);
            t2 = fmaf(an.z, row2, t2); t2 -= rintf(t2);
            const float e2 = __expf(an.x * row2);
            const float p2r = e2 * __builtin_amdgcn_cosf(t2);
            const float p2i = e2 * __builtin_amdgcn_sinf(t2);

            float zr = c.x * p0r - c.y * p0i;      // tm=0
            float zi = c.x * p0i + c.y * p0r;
            _Float16 zrh = (_Float16)zr, zih = (_Float16)zi;
            ahi[0][0][j] = zrh; alo[0][0][j] = (_Float16)(zr - (float)zrh);
            ahi[0][1][j] = zih; alo[0][1][j] = (_Float16)(zi - (float)zih);

            float yr = fmaf(zr, G.x, -(zi * G.y)); // tm=1 = z0*G
            float yi = fmaf(zr, G.y,  (zi * G.x));
            zrh = (_Float16)yr; zih = (_Float16)yi;
            ahi[1][0][j] = zrh; alo[1][0][j] = (_Float16)(yr - (float)zrh);
            ahi[1][1][j] = zih; alo[1][1][j] = (_Float16)(yi - (float)zih);

            zr = c.x * p2r - c.y * p2i;            // tm=2
            zi = c.x * p2i + c.y * p2r;
            zrh = (_Float16)zr; zih = (_Float16)zi;
            ahi[2][0][j] = zrh; alo[2][0][j] = (_Float16)(zr - (float)zrh);
            ahi[2][1][j] = zih; alo[2][1][j] = (_Float16)(zi - (float)zih);

            yr = fmaf(zr, G.x, -(zi * G.y));       // tm=3 = z2*G
            yi = fmaf(zr, G.y,  (zi * G.x));
            zrh = (_Float16)yr; zih = (_Float16)yi;
            ahi[3][0][j] = zrh; alo[3][0][j] = (_Float16)(yr - (float)zrh);
            ahi[3][1][j] = zih; alo[3][1][j] = (_Float16)(yi - (float)zih);
        }
    }
    __syncthreads();

    // ---- stage 4: GEMM (16 tiles x 6 MFMA) + nontemporal stores ----
    const size_t HL = (size_t)H * (size_t)L;
    float* obase = out + (size_t)w * HL + (size_t)h * (size_t)L;

#pragma unroll
    for (int tn = 0; tn < 4; ++tn) {
        const int brow = 16 * tn + l15;
        const half8 bh0 = *(const half8*)&Bt_hi[brow][ 8 * lgrp];
        const half8 bh1 = *(const half8*)&Bt_hi[brow][32 + 8 * lgrp];
        const half8 bl0 = *(const half8*)&Bt_lo[brow][ 8 * lgrp];
        const half8 bl1 = *(const half8*)&Bt_lo[brow][32 + 8 * lgrp];
#pragma unroll
        for (int tm = 0; tm < 4; ++tm) {
            f32x4 acc = {0.f, 0.f, 0.f, 0.f};
            acc = __builtin_amdgcn_mfma_f32_16x16x32_f16(ahi[tm][0], bh0, acc, 0, 0, 0);
            acc = __builtin_amdgcn_mfma_f32_16x16x32_f16(ahi[tm][1], bh1, acc, 0, 0, 0);
            acc = __builtin_amdgcn_mfma_f32_16x16x32_f16(ahi[tm][0], bl0, acc, 0, 0, 0);
            acc = __builtin_amdgcn_mfma_f32_16x16x32_f16(ahi[tm][1], bl1, acc, 0, 0, 0);
            acc = __builtin_amdgcn_mfma_f32_16x16x32_f16(alo[tm][0], bh0, acc, 0, 0, 0);
            acc = __builtin_amdgcn_mfma_f32_16x16x32_f16(alo[tm][1], bh1, acc, 0, 0, 0);
#pragma unroll
            for (int i = 0; i < 4; ++i) {
                const int r = 16 * tm + 4 * lgrp + i;       // l1
                __builtin_nontemporal_store(acc[i], &obase[64 * r + 16 * tn + l15]);
            }
        }
    }
}

extern "C" void kernel_launch(void* const* d_in, const int* in_sizes, int n_in,
                              void* d_out, int out_size, void* d_ws, size_t ws_size,
                              hipStream_t stream) {
    const float* C_r        = (const float*)d_in[0];
    const float* Ca_r       = (const float*)d_in[1];
    const float* E_r        = (const float*)d_in[2];
    const float* log_dt     = (const float*)d_in[3];
    const float* log_A_real = (const float*)d_in[4];
    const float* A_imag     = (const float*)d_in[5];
    float* out = (float*)d_out;

    const int H  = in_sizes[3];
    const int N2 = in_sizes[4] / H;     // 32
    const int L  = out_size / (4 * H);  // 4096 = 64*64

    dim3 grid(H);
    dim3 block(256);
    s4d_mfma_kernel<<<grid, block, 0, stream>>>(
        C_r, Ca_r, E_r, log_dt, log_A_real, A_imag, out, H, N2, L);
}